// Round 2
// baseline (718.508 us; speedup 1.0000x reference)
//
#include <hip/hip_runtime.h>
#include <math.h>

#define DIM 128

// ---------------------------------------------------------------- utilities
__global__ void k_zero_int(int* __restrict__ p, int n) {
    int i = blockIdx.x * blockDim.x + threadIdx.x;
    if (i < n) p[i] = 0;
}

// histogram of in-degrees: cnt[dst[e]]++
__global__ void k_hist(const int* __restrict__ dst, int* __restrict__ cnt, int E) {
    int e = blockIdx.x * blockDim.x + threadIdx.x;
    if (e < E) atomicAdd(&cnt[dst[e]], 1);
}

// scan level 1: each block scans 1024 elements (4/thread), writes exclusive
// prefix into rs, block total into bsum[blockIdx.x].
__global__ void k_scan1(const int* __restrict__ cnt, int* __restrict__ rs,
                        int* __restrict__ bsum, int n) {
    __shared__ int sh[256];
    int t = threadIdx.x;
    int base = blockIdx.x * 1024 + t * 4;
    int v0 = (base + 0 < n) ? cnt[base + 0] : 0;
    int v1 = (base + 1 < n) ? cnt[base + 1] : 0;
    int v2 = (base + 2 < n) ? cnt[base + 2] : 0;
    int v3 = (base + 3 < n) ? cnt[base + 3] : 0;
    int s = v0 + v1 + v2 + v3;
    sh[t] = s;
    __syncthreads();
    int run = s;
    for (int off = 1; off < 256; off <<= 1) {
        int y = (t >= off) ? sh[t - off] : 0;
        __syncthreads();
        run += y;
        sh[t] = run;
        __syncthreads();
    }
    int excl = run - s;  // exclusive prefix of this thread's 4-group
    if (base + 0 < n) rs[base + 0] = excl;
    if (base + 1 < n) rs[base + 1] = excl + v0;
    if (base + 2 < n) rs[base + 2] = excl + v0 + v1;
    if (base + 3 < n) rs[base + 3] = excl + v0 + v1 + v2;
    if (t == 255) bsum[blockIdx.x] = run;  // block total
}

// scan level 2: single block scans nb (<=256) block sums in place (exclusive)
__global__ void k_scan2(int* __restrict__ bsum, int nb) {
    __shared__ int sh[256];
    int t = threadIdx.x;
    int v = (t < nb) ? bsum[t] : 0;
    sh[t] = v;
    __syncthreads();
    int run = v;
    for (int off = 1; off < 256; off <<= 1) {
        int y = (t >= off) ? sh[t - off] : 0;
        __syncthreads();
        run += y;
        sh[t] = run;
        __syncthreads();
    }
    if (t < nb) bsum[t] = run - v;
}

// scan level 3: add block offsets, copy to cursor, write rs[n]=E
__global__ void k_scan3(int* __restrict__ rs, const int* __restrict__ bsum,
                        int* __restrict__ cur, int n, int E) {
    int i = blockIdx.x * blockDim.x + threadIdx.x;
    if (i < n) {
        int r = rs[i] + bsum[i >> 10];
        rs[i] = r;
        cur[i] = r;
    }
    if (i == 0) rs[n] = E;
}

// fill CSR edge list: esrc[pos] = src[e] grouped by dst
__global__ void k_fill(const int* __restrict__ src, const int* __restrict__ dst,
                       int* __restrict__ cur, int* __restrict__ esrc, int E) {
    int e = blockIdx.x * blockDim.x + threadIdx.x;
    if (e < E) {
        int d = dst[e];
        int p = atomicAdd(&cur[d], 1);
        esrc[p] = src[e];
    }
}

// mean-aggregate: one wave per dst node. Each HALF-wave (32 lanes x float4 =
// 512B) covers a full 128-col row; halves take alternating edges; manual
// unroll-2 per half => 4 independent row-loads in flight per wave.
// msg[node] = sum_{e in CSR row} in[esrc[e]] / max(deg,1)
__global__ __launch_bounds__(256) void k_agg(const float* __restrict__ in,
                                             const int* __restrict__ rs,
                                             const int* __restrict__ esrc,
                                             float* __restrict__ msg, int N) {
    int w = threadIdx.x >> 6;            // wave within block
    int half = (threadIdx.x >> 5) & 1;   // half-wave id
    int l32 = threadIdx.x & 31;          // lane within half
    int node = blockIdx.x * 4 + w;
    if (node >= N) return;
    int beg = rs[node], end = rs[node + 1];
    int c = l32 * 4;
    float ax = 0.f, ay = 0.f, az = 0.f, aw = 0.f;
    int e = beg + half;                  // this half's first edge (stride 2)
    for (; e + 2 < end; e += 4) {        // unroll 2: edges e and e+2
        int s0 = esrc[e];
        int s1 = esrc[e + 2];
        float4 u = *(const float4*)(in + (size_t)s0 * DIM + c);
        float4 v = *(const float4*)(in + (size_t)s1 * DIM + c);
        ax += u.x + v.x;
        ay += u.y + v.y;
        az += u.z + v.z;
        aw += u.w + v.w;
    }
    if (e < end) {                       // at most one leftover per half
        int s0 = esrc[e];
        float4 u = *(const float4*)(in + (size_t)s0 * DIM + c);
        ax += u.x;
        ay += u.y;
        az += u.z;
        aw += u.w;
    }
    // combine the two halves (each holds a partial sum over its edge subset)
    ax += __shfl_xor(ax, 32);
    ay += __shfl_xor(ay, 32);
    az += __shfl_xor(az, 32);
    aw += __shfl_xor(aw, 32);
    if (half == 0) {
        float invd = 1.0f / fmaxf((float)(end - beg), 1.0f);
        float4 o;
        o.x = ax * invd;
        o.y = ay * invd;
        o.z = az * invd;
        o.w = aw * invd;
        *(float4*)(msg + (size_t)node * DIM + c) = o;
    }
}

// fused dual GEMM: out[m] = A[m] @ Ws^T + Hn[m] @ Wn^T + bias
// block: 256 threads, tile 64 rows x 128 cols, K chunks of 32 (concat K=256)
__global__ __launch_bounds__(256) void k_gemm(const float* __restrict__ A,
                                              const float* __restrict__ Hn,
                                              const float* __restrict__ Ws,
                                              const float* __restrict__ Wn,
                                              const float* __restrict__ bias,
                                              float* __restrict__ out, int N) {
    __shared__ float As[32][68];   // k-major, padded: 68*4=272B row, 16B aligned
    __shared__ float Bs[32][132];  // k-major, padded: 132*4=528B row, 16B aligned
    int tid = threadIdx.x;
    int tr = tid >> 5;  // 0..7  -> row group (8 rows each)
    int tc = tid & 31;  // 0..31 -> col group (4 cols each)
    int m0 = blockIdx.x * 64;

    float acc[8][4];
#pragma unroll
    for (int i = 0; i < 8; ++i)
#pragma unroll
        for (int j = 0; j < 4; ++j) acc[i][j] = 0.f;

    for (int kb = 0; kb < 256; kb += 32) {
        const float* srcA = (kb < 128) ? A : Hn;
        const float* srcB = (kb < 128) ? Ws : Wn;
        int ka = kb & 127;
        // stage A tile: 64 rows x 32 k = 512 float4, 2 per thread
#pragma unroll
        for (int i = 0; i < 2; ++i) {
            int fi = tid + i * 256;
            int row = fi >> 3, kq = fi & 7;
            int m = m0 + row;
            float4 v = make_float4(0.f, 0.f, 0.f, 0.f);
            if (m < N) v = *(const float4*)(srcA + (size_t)m * DIM + ka + kq * 4);
            As[kq * 4 + 0][row] = v.x;
            As[kq * 4 + 1][row] = v.y;
            As[kq * 4 + 2][row] = v.z;
            As[kq * 4 + 3][row] = v.w;
        }
        // stage B tile: 128 out x 32 k = 1024 float4, 4 per thread
#pragma unroll
        for (int i = 0; i < 4; ++i) {
            int fi = tid + i * 256;
            int o = fi >> 3, kq = fi & 7;
            float4 v = *(const float4*)(srcB + o * DIM + ka + kq * 4);
            Bs[kq * 4 + 0][o] = v.x;
            Bs[kq * 4 + 1][o] = v.y;
            Bs[kq * 4 + 2][o] = v.z;
            Bs[kq * 4 + 3][o] = v.w;
        }
        __syncthreads();
#pragma unroll
        for (int kk = 0; kk < 32; ++kk) {
            float4 a0 = *(const float4*)&As[kk][tr * 8];
            float4 a1 = *(const float4*)&As[kk][tr * 8 + 4];
            float4 bv = *(const float4*)&Bs[kk][tc * 4];
            float av[8] = {a0.x, a0.y, a0.z, a0.w, a1.x, a1.y, a1.z, a1.w};
            float bw[4] = {bv.x, bv.y, bv.z, bv.w};
#pragma unroll
            for (int i = 0; i < 8; ++i)
#pragma unroll
                for (int j = 0; j < 4; ++j) acc[i][j] += av[i] * bw[j];
        }
        __syncthreads();
    }
    float4 bb = *(const float4*)(bias + tc * 4);
#pragma unroll
    for (int i = 0; i < 8; ++i) {
        int m = m0 + tr * 8 + i;
        if (m < N) {
            float4 o;
            o.x = acc[i][0] + bb.x;
            o.y = acc[i][1] + bb.y;
            o.z = acc[i][2] + bb.z;
            o.w = acc[i][3] + bb.w;
            *(float4*)(out + (size_t)m * DIM + tc * 4) = o;
        }
    }
}

// L2-normalize rows in place: one wave per node
__global__ __launch_bounds__(256) void k_norm(float* __restrict__ h, int N) {
    int w = threadIdx.x >> 6;
    int lane = threadIdx.x & 63;
    int node = blockIdx.x * 4 + w;
    if (node >= N) return;
    float2 v = *(float2*)(h + (size_t)node * DIM + lane * 2);
    float ss = v.x * v.x + v.y * v.y;
    for (int off = 32; off; off >>= 1) ss += __shfl_xor(ss, off);
    float norm = sqrtf(ss);
    float scale = 1.0f / fmaxf(norm, 1e-12f);
    float2 o;
    o.x = v.x * scale;
    o.y = v.y * scale;
    *(float2*)(h + (size_t)node * DIM + lane * 2) = o;
}

extern "C" void kernel_launch(void* const* d_in, const int* in_sizes, int n_in,
                              void* d_out, int out_size, void* d_ws, size_t ws_size,
                              hipStream_t stream) {
    const float* x   = (const float*)d_in[0];
    const int*   src = (const int*)d_in[1];
    const int*   dst = (const int*)d_in[2];
    const float* Ws1 = (const float*)d_in[3];
    const float* Wn1 = (const float*)d_in[4];
    const float* b1  = (const float*)d_in[5];
    const float* Ws2 = (const float*)d_in[6];
    const float* Wn2 = (const float*)d_in[7];
    const float* b2  = (const float*)d_in[8];
    float* out = (float*)d_out;

    int N = in_sizes[0] / DIM;
    int E = in_sizes[1];
    int nb1 = (N + 1023) / 1024;

    // workspace carve-up (all 256B aligned)
    char* p = (char*)d_ws;
    size_t off = 0;
    auto carve = [&](size_t bytes) {
        void* r = p + off;
        off = (off + bytes + 255) & ~(size_t)255;
        return r;
    };
    int* rs    = (int*)carve((size_t)(N + 1) * 4);
    int* cur   = (int*)carve((size_t)N * 4);
    int* bsum  = (int*)carve((size_t)nb1 * 4);
    int* esrc  = (int*)carve((size_t)E * 4);
    float* msg = (float*)carve((size_t)N * DIM * 4);
    float* h1  = (float*)carve((size_t)N * DIM * 4);

    // ---- CSR build (once; reused by both layers) ----
    k_zero_int<<<(N + 255) / 256, 256, 0, stream>>>(cur, N);
    k_hist<<<(E + 255) / 256, 256, 0, stream>>>(dst, cur, E);
    k_scan1<<<nb1, 256, 0, stream>>>(cur, rs, bsum, N);
    k_scan2<<<1, 256, 0, stream>>>(bsum, nb1);
    k_scan3<<<(N + 255) / 256, 256, 0, stream>>>(rs, bsum, cur, N, E);
    k_fill<<<(E + 255) / 256, 256, 0, stream>>>(src, dst, cur, esrc, E);

    // ---- layer 1 ----
    k_agg<<<(N + 3) / 4, 256, 0, stream>>>(x, rs, esrc, msg, N);
    k_gemm<<<(N + 63) / 64, 256, 0, stream>>>(x, msg, Ws1, Wn1, b1, h1, N);

    // ---- layer 2 ----
    k_agg<<<(N + 3) / 4, 256, 0, stream>>>(h1, rs, esrc, msg, N);
    k_gemm<<<(N + 63) / 64, 256, 0, stream>>>(h1, msg, Ws2, Wn2, b2, out, N);

    // ---- final row L2-normalize ----
    k_norm<<<(N + 3) / 4, 256, 0, stream>>>(out, N);
}